// Round 13
// baseline (112.096 us; speedup 1.0000x reference)
//
#include <hip/hip_runtime.h>
#include <math.h>

// Problem constants
#define B_ 8
#define T_ 256
#define A_ 2
#define C_ 128
#define R_ 128
#define H_ 128
#define OUT_ 256

// Workspace layout (float offsets)
#define WS_PCK 0
#define WS_PCV 16384
#define WS_PSK 32768
#define WS_PSV 33792
#define WS_QK  34816
// Taylor-coefficient planes (r-contiguous, [B][C][R]) + S0 [B][R]
#define WS_W1  36864
#define WS_W2  167936
#define WS_W3  299008
#define WS_S0  430080
#define WS_TOTAL 431104  // floats (~1.7 MB)

// gelu via A&S 7.1.27 (|erf err| <= 5e-4), no exp, branchless (scores path).
__device__ __forceinline__ float gelu_fast(float x) {
    const float ax = fabsf(x);
    float q = fmaf(ax, 0.019527f, 0.000343654f);
    q = fmaf(q, ax, 0.1151945f);
    q = fmaf(q, ax, 0.19685217f);
    q = fmaf(q, ax, 1.0f);
    const float r  = __builtin_amdgcn_rcpf(q);
    const float r2 = r * r;
    const float r4 = r2 * r2;
    return fmaf(-0.5f * ax, r4, fmaxf(x, 0.0f));
}

// ---------------------------------------------------------------------------
// Kernel 1: small projection dots into workspace.
// ---------------------------------------------------------------------------
__global__ __launch_bounds__(256) void prep_kernel(
    const float* __restrict__ session,   // [B,H]
    const float* __restrict__ query,     // [R]
    const float* __restrict__ pos,       // [C,R]
    const float* __restrict__ kW1,       // [R+H, R]
    const float* __restrict__ kb1,       // [R]
    const float* __restrict__ kW2,       // [R, R]
    const float* __restrict__ vW1,       // [R+H+1, R]
    const float* __restrict__ vb1,       // [R]
    float* __restrict__ ws)
{
    const int g = blockIdx.x * 256 + threadIdx.x;
    if (g < 16384) {                       // pck[c][r]
        const int c = g >> 7, r = g & 127;
        float acc = 0.0f;
        #pragma unroll 16
        for (int k = 0; k < R_; ++k)
            acc += pos[c * R_ + k] * kW1[k * R_ + r];
        ws[WS_PCK + g] = acc;
    } else if (g < 32768) {                // pcv[c][r]
        const int e = g - 16384;
        const int c = e >> 7, r = e & 127;
        float acc = 0.0f;
        #pragma unroll 16
        for (int k = 0; k < R_; ++k)
            acc += pos[c * R_ + k] * vW1[k * R_ + r];
        ws[WS_PCV + e] = acc;
    } else if (g < 33792) {                // psk[b][r] (+kb1)
        const int e = g - 32768;
        const int b = e >> 7, r = e & 127;
        float acc = kb1[r];
        #pragma unroll 16
        for (int k = 0; k < H_; ++k)
            acc += session[b * H_ + k] * kW1[(R_ + k) * R_ + r];
        ws[WS_PSK + e] = acc;
    } else if (g < 34816) {                // psv[b][r] (+vb1)
        const int e = g - 33792;
        const int b = e >> 7, r = e & 127;
        float acc = vb1[r];
        #pragma unroll 16
        for (int k = 0; k < H_; ++k)
            acc += session[b * H_ + k] * vW1[(R_ + k) * R_ + r];
        ws[WS_PSV + e] = acc;
    } else if (g < 34944) {                // qk[r] = kW2[r,:] . query
        const int r = g - 34816;
        float acc = 0.0f;
        #pragma unroll 16
        for (int j = 0; j < R_; ++j)
            acc += kW2[r * R_ + j] * query[j];
        ws[WS_QK + r] = acc;
    }
}

// ---------------------------------------------------------------------------
// Kernel 2 (fused): scores + softmax + Taylor coefficient planes.
// 8 blocks x 1024 threads.  (unchanged)
// ---------------------------------------------------------------------------
__global__ __launch_bounds__(1024) void softmax_coef_kernel(
    const float* __restrict__ vW1,    // [R+H+1, R]; last row = vr
    float* __restrict__ ws)
{
    __shared__ float pskL[R_];
    __shared__ float qkL[R_];
    __shared__ float part8[8][C_];
    __shared__ float sc[C_];
    __shared__ float red[C_];
    __shared__ float wL[C_];

    const int b   = blockIdx.x;
    const int tid = threadIdx.x;
    const int q   = tid >> 7;        // 0..7
    const int c   = tid & 127;

    if (tid < 128) {
        pskL[tid] = ws[WS_PSK + b * R_ + tid];
        qkL[tid]  = ws[WS_QK + tid];
    }
    __syncthreads();

    // scores: segment q covers r in [16q, 16q+16)
    const float* __restrict__ pckc = ws + WS_PCK + c * R_ + q * 16;
    float acc = 0.0f;
    #pragma unroll
    for (int i = 0; i < 16; ++i) {
        const float x = pckc[i] + pskL[q * 16 + i];
        acc += gelu_fast(x) * qkL[q * 16 + i];
    }
    part8[q][c] = acc;
    __syncthreads();

    if (tid < 128) {
        float s = part8[0][tid];
        #pragma unroll
        for (int j = 1; j < 8; ++j) s += part8[j][tid];
        s *= 0.08838834764831845f;   // 1/sqrt(128)
        sc[tid]  = s;
        red[tid] = s;
    }
    __syncthreads();
    for (int st = 64; st > 0; st >>= 1) {
        if (tid < st) red[tid] = fmaxf(red[tid], red[tid + st]);
        __syncthreads();
    }
    const float m = red[0];
    __syncthreads();
    if (tid < 128) {
        const float e = __expf(sc[tid] - m);
        sc[tid]  = e;
        red[tid] = e;
    }
    __syncthreads();
    for (int st = 64; st > 0; st >>= 1) {
        if (tid < st) red[tid] += red[tid + st];
        __syncthreads();
    }
    if (tid < 128) wL[tid] = sc[tid] / red[0];
    __syncthreads();

    // ---- coef phase: W_k[b,c,r] = w[c]*g_k(cc)*vr^k, S0[b,r] = sum w*g0 ----
    const int r  = c;
    const int cq = q;
    const float vr  = vW1[(R_ + H_) * R_ + r];
    const float vr2 = vr * vr;
    const float vr3 = vr2 * vr;
    const float psv_r = ws[WS_PSV + b * R_ + r];

    float s0acc = 0.0f;
    #pragma unroll 4
    for (int i = 0; i < 16; ++i) {
        const int c2 = cq * 16 + i;
        const float cc  = ws[WS_PCV + c2 * R_ + r] + psv_r;
        const float wgt = wL[c2];
        // Phi(cc) via A&S 7.1.27 on |cc| (coeffs pre-folded with 1/sqrt2)
        const float ax = fabsf(cc);
        float qq = fmaf(ax, 0.019527f, 0.000343654f);
        qq = fmaf(qq, ax, 0.1151945f);
        qq = fmaf(qq, ax, 0.19685217f);
        qq = fmaf(qq, ax, 1.0f);
        const float qi  = __builtin_amdgcn_rcpf(qq);
        const float qi2 = qi * qi;
        const float h   = 0.5f * qi2 * qi2;          // = Phi(-|cc|)
        const float Phi = (cc >= 0.0f) ? (1.0f - h) : h;
        const float cc2 = cc * cc;
        const float phi = 0.3989422804f * __expf(-0.5f * cc2);
        const float g0 = cc * Phi;
        const float g1 = fmaf(cc, phi, Phi);
        const float g2 = 0.5f * phi * (2.0f - cc2);
        const float g3 = phi * cc * (cc2 - 4.0f) * (1.0f / 6.0f);
        const size_t idx = (size_t)(b * C_ + c2) * R_ + r;
        ws[WS_W1 + idx] = wgt * g1 * vr;
        ws[WS_W2 + idx] = wgt * g2 * vr2;
        ws[WS_W3 + idx] = wgt * g3 * vr3;
        s0acc += wgt * g0;
    }
    part8[cq][r] = s0acc;            // reuse part8 for the S0 reduction
    __syncthreads();
    if (tid < 128) {
        float s = part8[0][tid];
        #pragma unroll
        for (int j = 1; j < 8; ++j) s += part8[j][tid];
        ws[WS_S0 + b * R_ + tid] = s;
    }
}

// ---------------------------------------------------------------------------
// Kernel 3: main. 256 blocks x 256 threads; SIXTEEN (t,a) rows per block
// (exactly 1 block/CU).  Coef-plane traffic halves again (100->50 MB);
// the hot loop's 3 b128 loads/c-iter now feed 16 rows (~224 fma/iter) so
// arithmetic intensity doubles.  Transpose + split-K epilogue run as two
// 8-row passes over the same aliased 32 KB LDS (R12-validated structure).
// ---------------------------------------------------------------------------
__global__ __launch_bounds__(256) void main_kernel(
    const float* __restrict__ state,  // [B, 512, 128] rows
    const float* __restrict__ vW2,    // [R, OUT]
    const float* __restrict__ vb2,    // [OUT]
    const float* __restrict__ ws,
    float* __restrict__ out)          // [B, 512, OUT]
{
    __shared__ __align__(16) float sv[16 * C_];   // 16 state rows (8 KB)
    __shared__ float4 smem[2][8][R_];             // 32 KB: transpose scratch,
                                                  // then reused as ep[4][8][64]
    __shared__ float4 p4a[R_];                    // rows 0-3   combined
    __shared__ float4 p4b[R_];                    // rows 4-7
    __shared__ float4 p4c[R_];                    // rows 8-11
    __shared__ float4 p4d[R_];                    // rows 12-15

    const int blk = blockIdx.x;
    const int b   = blk >> 5;        // / 32
    const int grp = blk & 31;
    const int tid = threadIdx.x;
    const int k   = tid & 31;        // r-quad index: r0 = 4k
    const int seg = tid >> 5;        // c-segment: c in [16*seg, +16)
    const int r0  = k * 4;

    const float* __restrict__ srow = state + (size_t)(b * 512 + grp * 16) * C_;
    #pragma unroll
    for (int i = 0; i < 8; ++i) sv[tid + 256 * i] = srow[tid + 256 * i];
    __syncthreads();

    const size_t pbase = (size_t)(b * C_) * R_ + r0;
    const float* __restrict__ W1p = ws + WS_W1 + pbase;
    const float* __restrict__ W2p = ws + WS_W2 + pbase;
    const float* __restrict__ W3p = ws + WS_W3 + pbase;

    float4 a[16];
    #pragma unroll
    for (int j = 0; j < 16; ++j) a[j] = make_float4(0.f, 0.f, 0.f, 0.f);

    const int cbeg = seg * 16;
    #pragma unroll 2
    for (int i = 0; i < 16; ++i) {
        const int c = cbeg + i;
        const float4 w1 = *(const float4*)(W1p + (size_t)c * R_);  // b128
        const float4 w2 = *(const float4*)(W2p + (size_t)c * R_);  // b128
        const float4 w3 = *(const float4*)(W3p + (size_t)c * R_);  // b128
        #pragma unroll
        for (int j = 0; j < 16; ++j) {
            const float s  = sv[j * C_ + c];
            const float s2 = s * s;
            const float s3 = s2 * s;
            a[j].x = fmaf(w1.x, s, a[j].x); a[j].x = fmaf(w2.x, s2, a[j].x); a[j].x = fmaf(w3.x, s3, a[j].x);
            a[j].y = fmaf(w1.y, s, a[j].y); a[j].y = fmaf(w2.y, s2, a[j].y); a[j].y = fmaf(w3.y, s3, a[j].y);
            a[j].z = fmaf(w1.z, s, a[j].z); a[j].z = fmaf(w2.z, s2, a[j].z); a[j].z = fmaf(w3.z, s3, a[j].z);
            a[j].w = fmaf(w1.w, s, a[j].w); a[j].w = fmaf(w2.w, s2, a[j].w); a[j].w = fmaf(w3.w, s3, a[j].w);
        }
    }

    const float s0v_all = (tid < 128) ? ws[WS_S0 + b * R_ + tid] : 0.0f;

    // ---- transpose + combine, two 8-row passes over the same smem ----
    #pragma unroll
    for (int pass = 0; pass < 2; ++pass) {
        const int jb = pass * 8;
        smem[0][seg][r0 + 0] = make_float4(a[jb+0].x, a[jb+1].x, a[jb+2].x, a[jb+3].x);
        smem[0][seg][r0 + 1] = make_float4(a[jb+0].y, a[jb+1].y, a[jb+2].y, a[jb+3].y);
        smem[0][seg][r0 + 2] = make_float4(a[jb+0].z, a[jb+1].z, a[jb+2].z, a[jb+3].z);
        smem[0][seg][r0 + 3] = make_float4(a[jb+0].w, a[jb+1].w, a[jb+2].w, a[jb+3].w);
        smem[1][seg][r0 + 0] = make_float4(a[jb+4].x, a[jb+5].x, a[jb+6].x, a[jb+7].x);
        smem[1][seg][r0 + 1] = make_float4(a[jb+4].y, a[jb+5].y, a[jb+6].y, a[jb+7].y);
        smem[1][seg][r0 + 2] = make_float4(a[jb+4].z, a[jb+5].z, a[jb+6].z, a[jb+7].z);
        smem[1][seg][r0 + 3] = make_float4(a[jb+4].w, a[jb+5].w, a[jb+6].w, a[jb+7].w);
        __syncthreads();
        if (tid < 128) {
            float4 lo = smem[0][0][tid];
            float4 hi = smem[1][0][tid];
            #pragma unroll
            for (int sg = 1; sg < 8; ++sg) {
                const float4 tl = smem[0][sg][tid];
                const float4 th = smem[1][sg][tid];
                lo.x += tl.x; lo.y += tl.y; lo.z += tl.z; lo.w += tl.w;
                hi.x += th.x; hi.y += th.y; hi.z += th.z; hi.w += th.w;
            }
            lo.x += s0v_all; lo.y += s0v_all; lo.z += s0v_all; lo.w += s0v_all;
            hi.x += s0v_all; hi.y += s0v_all; hi.z += s0v_all; hi.w += s0v_all;
            if (pass == 0) { p4a[tid] = lo; p4b[tid] = hi; }
            else           { p4c[tid] = lo; p4d[tid] = hi; }
        }
        __syncthreads();
    }

    // ---- epilogue: split-K register-tiled GEMM, two 8-row passes ----
    float4 (*ep)[8][64] = (float4 (*)[8][64])smem;   // [kq][row][hq], 32 KB
    const int hq = tid & 63;
    const int kq = tid >> 6;
    const int h0 = hq * 4;
    const int rrb = kq * 32;
    const int row  = tid >> 5;
    const int hqa  = tid & 31;

    #pragma unroll
    for (int pass = 0; pass < 2; ++pass) {
        const float4* __restrict__ plo4 = (pass == 0) ? p4a : p4c;
        const float4* __restrict__ phi4 = (pass == 0) ? p4b : p4d;
        float4 o[8];
        #pragma unroll
        for (int j = 0; j < 8; ++j) o[j] = make_float4(0.f, 0.f, 0.f, 0.f);
        #pragma unroll 4
        for (int i = 0; i < 32; ++i) {
            const int rr = rrb + i;
            const float4 plo = plo4[rr];                               // broadcast
            const float4 phi = phi4[rr];                               // broadcast
            const float4 wv4 = *(const float4*)(vW2 + rr * OUT_ + h0); // coalesced
            o[0].x = fmaf(plo.x, wv4.x, o[0].x); o[0].y = fmaf(plo.x, wv4.y, o[0].y);
            o[0].z = fmaf(plo.x, wv4.z, o[0].z); o[0].w = fmaf(plo.x, wv4.w, o[0].w);
            o[1].x = fmaf(plo.y, wv4.x, o[1].x); o[1].y = fmaf(plo.y, wv4.y, o[1].y);
            o[1].z = fmaf(plo.y, wv4.z, o[1].z); o[1].w = fmaf(plo.y, wv4.w, o[1].w);
            o[2].x = fmaf(plo.z, wv4.x, o[2].x); o[2].y = fmaf(plo.z, wv4.y, o[2].y);
            o[2].z = fmaf(plo.z, wv4.z, o[2].z); o[2].w = fmaf(plo.z, wv4.w, o[2].w);
            o[3].x = fmaf(plo.w, wv4.x, o[3].x); o[3].y = fmaf(plo.w, wv4.y, o[3].y);
            o[3].z = fmaf(plo.w, wv4.z, o[3].z); o[3].w = fmaf(plo.w, wv4.w, o[3].w);
            o[4].x = fmaf(phi.x, wv4.x, o[4].x); o[4].y = fmaf(phi.x, wv4.y, o[4].y);
            o[4].z = fmaf(phi.x, wv4.z, o[4].z); o[4].w = fmaf(phi.x, wv4.w, o[4].w);
            o[5].x = fmaf(phi.y, wv4.x, o[5].x); o[5].y = fmaf(phi.y, wv4.y, o[5].y);
            o[5].z = fmaf(phi.y, wv4.z, o[5].z); o[5].w = fmaf(phi.y, wv4.w, o[5].w);
            o[6].x = fmaf(phi.z, wv4.x, o[6].x); o[6].y = fmaf(phi.z, wv4.y, o[6].y);
            o[6].z = fmaf(phi.z, wv4.z, o[6].z); o[6].w = fmaf(phi.z, wv4.w, o[6].w);
            o[7].x = fmaf(phi.w, wv4.x, o[7].x); o[7].y = fmaf(phi.w, wv4.y, o[7].y);
            o[7].z = fmaf(phi.w, wv4.z, o[7].z); o[7].w = fmaf(phi.w, wv4.w, o[7].w);
        }
        #pragma unroll
        for (int j = 0; j < 8; ++j) ep[kq][j][hq] = o[j];
        __syncthreads();

        float* __restrict__ orow = out
            + (size_t)(b * 512 + grp * 16 + pass * 8 + row) * OUT_;
        #pragma unroll
        for (int half = 0; half < 2; ++half) {
            const int hh = hqa + half * 32;
            const float4 e0 = ep[0][row][hh];
            const float4 e1 = ep[1][row][hh];
            const float4 e2 = ep[2][row][hh];
            const float4 e3 = ep[3][row][hh];
            const float4 bias = *(const float4*)(vb2 + hh * 4);
            float4 oo;
            oo.x = e0.x + e1.x + e2.x + e3.x + bias.x;
            oo.y = e0.y + e1.y + e2.y + e3.y + bias.y;
            oo.z = e0.z + e1.z + e2.z + e3.z + bias.z;
            oo.w = e0.w + e1.w + e2.w + e3.w + bias.w;
            *(float4*)(orow + hh * 4) = oo;        // b128 coalesced store
        }
        __syncthreads();   // ep reused next pass
    }
}

extern "C" void kernel_launch(void* const* d_in, const int* in_sizes, int n_in,
                              void* d_out, int out_size, void* d_ws, size_t ws_size,
                              hipStream_t stream) {
    const float* state   = (const float*)d_in[0];   // [B,T,A,C]
    const float* session = (const float*)d_in[1];   // [B,H]
    const float* query   = (const float*)d_in[4];   // [R]
    const float* pos     = (const float*)d_in[5];   // [C,R]
    const float* kW1     = (const float*)d_in[6];   // [R+H, R]
    const float* kb1     = (const float*)d_in[7];   // [R]
    const float* kW2     = (const float*)d_in[8];   // [R, R]
    const float* vW1     = (const float*)d_in[10];  // [R+H+1, R]
    const float* vb1     = (const float*)d_in[11];  // [R]
    const float* vW2     = (const float*)d_in[12];  // [R, OUT]
    const float* vb2     = (const float*)d_in[13];  // [OUT]

    float* ws  = (float*)d_ws;
    float* out = (float*)d_out;

    prep_kernel<<<137, 256, 0, stream>>>(session, query, pos, kW1, kb1, kW2,
                                         vW1, vb1, ws);
    softmax_coef_kernel<<<B_, 1024, 0, stream>>>(vW1, ws);
    main_kernel<<<B_ * 32, 256, 0, stream>>>(state, vW2, vb2, ws, out);
}

// Round 14
// 108.706 us; speedup vs baseline: 1.0312x; 1.0312x over previous
//
#include <hip/hip_runtime.h>
#include <math.h>

// Problem constants
#define B_ 8
#define T_ 256
#define A_ 2
#define C_ 128
#define R_ 128
#define H_ 128
#define OUT_ 256

// Workspace layout (float offsets)
#define WS_PCK 0
#define WS_PCV 16384
#define WS_PSK 32768
#define WS_PSV 33792
#define WS_QK  34816
// Taylor-coefficient planes (r-contiguous, [B][C][R]) + S0 [B][R]
#define WS_W1  36864
#define WS_W2  167936
#define WS_W3  299008
#define WS_S0  430080
#define WS_TOTAL 431104  // floats (~1.7 MB)

// gelu via A&S 7.1.27 (|erf err| <= 5e-4), no exp, branchless (scores path).
__device__ __forceinline__ float gelu_fast(float x) {
    const float ax = fabsf(x);
    float q = fmaf(ax, 0.019527f, 0.000343654f);
    q = fmaf(q, ax, 0.1151945f);
    q = fmaf(q, ax, 0.19685217f);
    q = fmaf(q, ax, 1.0f);
    const float r  = __builtin_amdgcn_rcpf(q);
    const float r2 = r * r;
    const float r4 = r2 * r2;
    return fmaf(-0.5f * ax, r4, fmaxf(x, 0.0f));
}

// ---------------------------------------------------------------------------
// Kernel 1: small projection dots into workspace.
// ---------------------------------------------------------------------------
__global__ __launch_bounds__(256) void prep_kernel(
    const float* __restrict__ session,   // [B,H]
    const float* __restrict__ query,     // [R]
    const float* __restrict__ pos,       // [C,R]
    const float* __restrict__ kW1,       // [R+H, R]
    const float* __restrict__ kb1,       // [R]
    const float* __restrict__ kW2,       // [R, R]
    const float* __restrict__ vW1,       // [R+H+1, R]
    const float* __restrict__ vb1,       // [R]
    float* __restrict__ ws)
{
    const int g = blockIdx.x * 256 + threadIdx.x;
    if (g < 16384) {                       // pck[c][r]
        const int c = g >> 7, r = g & 127;
        float acc = 0.0f;
        #pragma unroll 16
        for (int k = 0; k < R_; ++k)
            acc += pos[c * R_ + k] * kW1[k * R_ + r];
        ws[WS_PCK + g] = acc;
    } else if (g < 32768) {                // pcv[c][r]
        const int e = g - 16384;
        const int c = e >> 7, r = e & 127;
        float acc = 0.0f;
        #pragma unroll 16
        for (int k = 0; k < R_; ++k)
            acc += pos[c * R_ + k] * vW1[k * R_ + r];
        ws[WS_PCV + e] = acc;
    } else if (g < 33792) {                // psk[b][r] (+kb1)
        const int e = g - 32768;
        const int b = e >> 7, r = e & 127;
        float acc = kb1[r];
        #pragma unroll 16
        for (int k = 0; k < H_; ++k)
            acc += session[b * H_ + k] * kW1[(R_ + k) * R_ + r];
        ws[WS_PSK + e] = acc;
    } else if (g < 34816) {                // psv[b][r] (+vb1)
        const int e = g - 33792;
        const int b = e >> 7, r = e & 127;
        float acc = vb1[r];
        #pragma unroll 16
        for (int k = 0; k < H_; ++k)
            acc += session[b * H_ + k] * vW1[(R_ + k) * R_ + r];
        ws[WS_PSV + e] = acc;
    } else if (g < 34944) {                // qk[r] = kW2[r,:] . query
        const int r = g - 34816;
        float acc = 0.0f;
        #pragma unroll 16
        for (int j = 0; j < R_; ++j)
            acc += kW2[r * R_ + j] * query[j];
        ws[WS_QK + r] = acc;
    }
}

// ---------------------------------------------------------------------------
// Kernel 2 (fused): scores + softmax + Taylor coefficient planes.
// 8 blocks x 1024 threads.
// ---------------------------------------------------------------------------
__global__ __launch_bounds__(1024) void softmax_coef_kernel(
    const float* __restrict__ vW1,    // [R+H+1, R]; last row = vr
    float* __restrict__ ws)
{
    __shared__ float pskL[R_];
    __shared__ float qkL[R_];
    __shared__ float part8[8][C_];
    __shared__ float sc[C_];
    __shared__ float red[C_];
    __shared__ float wL[C_];

    const int b   = blockIdx.x;
    const int tid = threadIdx.x;
    const int q   = tid >> 7;        // 0..7
    const int c   = tid & 127;

    if (tid < 128) {
        pskL[tid] = ws[WS_PSK + b * R_ + tid];
        qkL[tid]  = ws[WS_QK + tid];
    }
    __syncthreads();

    // scores: segment q covers r in [16q, 16q+16)
    const float* __restrict__ pckc = ws + WS_PCK + c * R_ + q * 16;
    float acc = 0.0f;
    #pragma unroll
    for (int i = 0; i < 16; ++i) {
        const float x = pckc[i] + pskL[q * 16 + i];
        acc += gelu_fast(x) * qkL[q * 16 + i];
    }
    part8[q][c] = acc;
    __syncthreads();

    if (tid < 128) {
        float s = part8[0][tid];
        #pragma unroll
        for (int j = 1; j < 8; ++j) s += part8[j][tid];
        s *= 0.08838834764831845f;   // 1/sqrt(128)
        sc[tid]  = s;
        red[tid] = s;
    }
    __syncthreads();
    for (int st = 64; st > 0; st >>= 1) {
        if (tid < st) red[tid] = fmaxf(red[tid], red[tid + st]);
        __syncthreads();
    }
    const float m = red[0];
    __syncthreads();
    if (tid < 128) {
        const float e = __expf(sc[tid] - m);
        sc[tid]  = e;
        red[tid] = e;
    }
    __syncthreads();
    for (int st = 64; st > 0; st >>= 1) {
        if (tid < st) red[tid] += red[tid + st];
        __syncthreads();
    }
    if (tid < 128) wL[tid] = sc[tid] / red[0];
    __syncthreads();

    // ---- coef phase: W_k[b,c,r] = w[c]*g_k(cc)*vr^k, S0[b,r] = sum w*g0 ----
    const int r  = c;
    const int cq = q;
    const float vr  = vW1[(R_ + H_) * R_ + r];
    const float vr2 = vr * vr;
    const float vr3 = vr2 * vr;
    const float psv_r = ws[WS_PSV + b * R_ + r];

    float s0acc = 0.0f;
    #pragma unroll 4
    for (int i = 0; i < 16; ++i) {
        const int c2 = cq * 16 + i;
        const float cc  = ws[WS_PCV + c2 * R_ + r] + psv_r;
        const float wgt = wL[c2];
        // Phi(cc) via A&S 7.1.27 on |cc| (coeffs pre-folded with 1/sqrt2)
        const float ax = fabsf(cc);
        float qq = fmaf(ax, 0.019527f, 0.000343654f);
        qq = fmaf(qq, ax, 0.1151945f);
        qq = fmaf(qq, ax, 0.19685217f);
        qq = fmaf(qq, ax, 1.0f);
        const float qi  = __builtin_amdgcn_rcpf(qq);
        const float qi2 = qi * qi;
        const float h   = 0.5f * qi2 * qi2;          // = Phi(-|cc|)
        const float Phi = (cc >= 0.0f) ? (1.0f - h) : h;
        const float cc2 = cc * cc;
        const float phi = 0.3989422804f * __expf(-0.5f * cc2);
        const float g0 = cc * Phi;
        const float g1 = fmaf(cc, phi, Phi);
        const float g2 = 0.5f * phi * (2.0f - cc2);
        const float g3 = phi * cc * (cc2 - 4.0f) * (1.0f / 6.0f);
        const size_t idx = (size_t)(b * C_ + c2) * R_ + r;
        ws[WS_W1 + idx] = wgt * g1 * vr;
        ws[WS_W2 + idx] = wgt * g2 * vr2;
        ws[WS_W3 + idx] = wgt * g3 * vr3;
        s0acc += wgt * g0;
    }
    part8[cq][r] = s0acc;            // reuse part8 for the S0 reduction
    __syncthreads();
    if (tid < 128) {
        float s = part8[0][tid];
        #pragma unroll
        for (int j = 1; j < 8; ++j) s += part8[j][tid];
        ws[WS_S0 + b * R_ + tid] = s;
    }
}

// ---------------------------------------------------------------------------
// Kernel 3: main. 512 blocks x 256 threads; EIGHT (t,a) rows per block.
// Measured optimum of the row-tiling curve (R10:4=113.4, R12:8=108.7,
// R13:16=112.1 -- 1 block/CU loses barrier overlap; 2 blocks/CU wins).
// ---------------------------------------------------------------------------
__global__ __launch_bounds__(256) void main_kernel(
    const float* __restrict__ state,  // [B, 512, 128] rows
    const float* __restrict__ vW2,    // [R, OUT]
    const float* __restrict__ vb2,    // [OUT]
    const float* __restrict__ ws,
    float* __restrict__ out)          // [B, 512, OUT]
{
    __shared__ __align__(16) float sv[8 * C_];    // 8 state rows (4 KB)
    __shared__ float4 smem[2][8][R_];             // 32 KB: transpose partials,
                                                  // then reused as ep[4][8][64]
    __shared__ float4 p4lo[R_];                   // combined partials rows 0-3
    __shared__ float4 p4hi[R_];                   // combined partials rows 4-7

    const int blk = blockIdx.x;
    const int b   = blk >> 6;        // / 64
    const int grp = blk & 63;
    const int tid = threadIdx.x;
    const int k   = tid & 31;        // r-quad index: r0 = 4k
    const int seg = tid >> 5;        // c-segment: c in [16*seg, +16)
    const int r0  = k * 4;

    const float* __restrict__ srow = state + (size_t)(b * 512 + grp * 8) * C_;
    #pragma unroll
    for (int i = 0; i < 4; ++i) sv[tid + 256 * i] = srow[tid + 256 * i];
    __syncthreads();

    const size_t pbase = (size_t)(b * C_) * R_ + r0;
    const float* __restrict__ W1p = ws + WS_W1 + pbase;
    const float* __restrict__ W2p = ws + WS_W2 + pbase;
    const float* __restrict__ W3p = ws + WS_W3 + pbase;

    float4 a[8];
    #pragma unroll
    for (int j = 0; j < 8; ++j) a[j] = make_float4(0.f, 0.f, 0.f, 0.f);

    const int cbeg = seg * 16;
    #pragma unroll 2
    for (int i = 0; i < 16; ++i) {
        const int c = cbeg + i;
        const float4 w1 = *(const float4*)(W1p + (size_t)c * R_);  // b128
        const float4 w2 = *(const float4*)(W2p + (size_t)c * R_);  // b128
        const float4 w3 = *(const float4*)(W3p + (size_t)c * R_);  // b128
        #pragma unroll
        for (int j = 0; j < 8; ++j) {
            const float s  = sv[j * C_ + c];
            const float s2 = s * s;
            const float s3 = s2 * s;
            a[j].x = fmaf(w1.x, s, a[j].x); a[j].x = fmaf(w2.x, s2, a[j].x); a[j].x = fmaf(w3.x, s3, a[j].x);
            a[j].y = fmaf(w1.y, s, a[j].y); a[j].y = fmaf(w2.y, s2, a[j].y); a[j].y = fmaf(w3.y, s3, a[j].y);
            a[j].z = fmaf(w1.z, s, a[j].z); a[j].z = fmaf(w2.z, s2, a[j].z); a[j].z = fmaf(w3.z, s3, a[j].z);
            a[j].w = fmaf(w1.w, s, a[j].w); a[j].w = fmaf(w2.w, s2, a[j].w); a[j].w = fmaf(w3.w, s3, a[j].w);
        }
    }

    // transpose: smem[0][seg][r] = rows0-3 partials, smem[1][seg][r] = rows4-7
    smem[0][seg][r0 + 0] = make_float4(a[0].x, a[1].x, a[2].x, a[3].x);
    smem[0][seg][r0 + 1] = make_float4(a[0].y, a[1].y, a[2].y, a[3].y);
    smem[0][seg][r0 + 2] = make_float4(a[0].z, a[1].z, a[2].z, a[3].z);
    smem[0][seg][r0 + 3] = make_float4(a[0].w, a[1].w, a[2].w, a[3].w);
    smem[1][seg][r0 + 0] = make_float4(a[4].x, a[5].x, a[6].x, a[7].x);
    smem[1][seg][r0 + 1] = make_float4(a[4].y, a[5].y, a[6].y, a[7].y);
    smem[1][seg][r0 + 2] = make_float4(a[4].z, a[5].z, a[6].z, a[7].z);
    smem[1][seg][r0 + 3] = make_float4(a[4].w, a[5].w, a[6].w, a[7].w);
    __syncthreads();

    if (tid < 128) {
        float4 lo = smem[0][0][tid];
        float4 hi = smem[1][0][tid];
        #pragma unroll
        for (int sg = 1; sg < 8; ++sg) {
            const float4 tl = smem[0][sg][tid];
            const float4 th = smem[1][sg][tid];
            lo.x += tl.x; lo.y += tl.y; lo.z += tl.z; lo.w += tl.w;
            hi.x += th.x; hi.y += th.y; hi.z += th.z; hi.w += th.w;
        }
        const float s0v = ws[WS_S0 + b * R_ + tid];  // row-independent term
        lo.x += s0v; lo.y += s0v; lo.z += s0v; lo.w += s0v;
        hi.x += s0v; hi.y += s0v; hi.z += s0v; hi.w += s0v;
        p4lo[tid] = lo;
        p4hi[tid] = hi;
    }
    __syncthreads();   // smem[] partials dead; reuse as ep[4][8][64]

    // Epilogue: split-K register-tiled GEMM, 8 rows x 4 h per thread.
    float4 (*ep)[8][64] = (float4 (*)[8][64])smem;   // [kq][row][hq], 32 KB
    const int hq = tid & 63;
    const int kq = tid >> 6;
    const int h0 = hq * 4;

    float4 o[8];
    #pragma unroll
    for (int j = 0; j < 8; ++j) o[j] = make_float4(0.f, 0.f, 0.f, 0.f);
    const int rrb = kq * 32;
    #pragma unroll 4
    for (int i = 0; i < 32; ++i) {
        const int rr = rrb + i;
        const float4 plo = p4lo[rr];                               // broadcast
        const float4 phi = p4hi[rr];                               // broadcast
        const float4 wv4 = *(const float4*)(vW2 + rr * OUT_ + h0); // coalesced
        o[0].x = fmaf(plo.x, wv4.x, o[0].x); o[0].y = fmaf(plo.x, wv4.y, o[0].y);
        o[0].z = fmaf(plo.x, wv4.z, o[0].z); o[0].w = fmaf(plo.x, wv4.w, o[0].w);
        o[1].x = fmaf(plo.y, wv4.x, o[1].x); o[1].y = fmaf(plo.y, wv4.y, o[1].y);
        o[1].z = fmaf(plo.y, wv4.z, o[1].z); o[1].w = fmaf(plo.y, wv4.w, o[1].w);
        o[2].x = fmaf(plo.z, wv4.x, o[2].x); o[2].y = fmaf(plo.z, wv4.y, o[2].y);
        o[2].z = fmaf(plo.z, wv4.z, o[2].z); o[2].w = fmaf(plo.z, wv4.w, o[2].w);
        o[3].x = fmaf(plo.w, wv4.x, o[3].x); o[3].y = fmaf(plo.w, wv4.y, o[3].y);
        o[3].z = fmaf(plo.w, wv4.z, o[3].z); o[3].w = fmaf(plo.w, wv4.w, o[3].w);
        o[4].x = fmaf(phi.x, wv4.x, o[4].x); o[4].y = fmaf(phi.x, wv4.y, o[4].y);
        o[4].z = fmaf(phi.x, wv4.z, o[4].z); o[4].w = fmaf(phi.x, wv4.w, o[4].w);
        o[5].x = fmaf(phi.y, wv4.x, o[5].x); o[5].y = fmaf(phi.y, wv4.y, o[5].y);
        o[5].z = fmaf(phi.y, wv4.z, o[5].z); o[5].w = fmaf(phi.y, wv4.w, o[5].w);
        o[6].x = fmaf(phi.z, wv4.x, o[6].x); o[6].y = fmaf(phi.z, wv4.y, o[6].y);
        o[6].z = fmaf(phi.z, wv4.z, o[6].z); o[6].w = fmaf(phi.z, wv4.w, o[6].w);
        o[7].x = fmaf(phi.w, wv4.x, o[7].x); o[7].y = fmaf(phi.w, wv4.y, o[7].y);
        o[7].z = fmaf(phi.w, wv4.z, o[7].z); o[7].w = fmaf(phi.w, wv4.w, o[7].w);
    }
    #pragma unroll
    for (int j = 0; j < 8; ++j) ep[kq][j][hq] = o[j];
    __syncthreads();

    // final combine: thread = (row = tid>>5, hq2 = tid&31 -> hq2, hq2+32)
    const int row  = tid >> 5;
    const int hqa  = tid & 31;
    float* __restrict__ orow = out + (size_t)(b * 512 + grp * 8) * OUT_ + row * OUT_;
    #pragma unroll
    for (int half = 0; half < 2; ++half) {
        const int hh = hqa + half * 32;
        const float4 e0 = ep[0][row][hh];
        const float4 e1 = ep[1][row][hh];
        const float4 e2 = ep[2][row][hh];
        const float4 e3 = ep[3][row][hh];
        const float4 bias = *(const float4*)(vb2 + hh * 4);
        float4 oo;
        oo.x = e0.x + e1.x + e2.x + e3.x + bias.x;
        oo.y = e0.y + e1.y + e2.y + e3.y + bias.y;
        oo.z = e0.z + e1.z + e2.z + e3.z + bias.z;
        oo.w = e0.w + e1.w + e2.w + e3.w + bias.w;
        *(float4*)(orow + hh * 4) = oo;        // b128 coalesced store
    }
}

extern "C" void kernel_launch(void* const* d_in, const int* in_sizes, int n_in,
                              void* d_out, int out_size, void* d_ws, size_t ws_size,
                              hipStream_t stream) {
    const float* state   = (const float*)d_in[0];   // [B,T,A,C]
    const float* session = (const float*)d_in[1];   // [B,H]
    const float* query   = (const float*)d_in[4];   // [R]
    const float* pos     = (const float*)d_in[5];   // [C,R]
    const float* kW1     = (const float*)d_in[6];   // [R+H, R]
    const float* kb1     = (const float*)d_in[7];   // [R]
    const float* kW2     = (const float*)d_in[8];   // [R, R]
    const float* vW1     = (const float*)d_in[10];  // [R+H+1, R]
    const float* vb1     = (const float*)d_in[11];  // [R]
    const float* vW2     = (const float*)d_in[12];  // [R, OUT]
    const float* vb2     = (const float*)d_in[13];  // [OUT]

    float* ws  = (float*)d_ws;
    float* out = (float*)d_out;

    prep_kernel<<<137, 256, 0, stream>>>(session, query, pos, kW1, kb1, kW2,
                                         vW1, vb1, ws);
    softmax_coef_kernel<<<B_, 1024, 0, stream>>>(vW1, ws);
    main_kernel<<<B_ * 64, 256, 0, stream>>>(state, vW2, vb2, ws, out);
}